// Round 1
// baseline (464.607 us; speedup 1.0000x reference)
//
#include <hip/hip_runtime.h>

// Problem constants
#define NB 4
#define NC 32
#define NPIX 262144   // 512*512
#define NI 8
#define NE 512
#define FEPS 1e-12f

// Workspace layout (float offsets)
#define WS_SUMS   0        // [4][8][32] = 1024
#define WS_CNT    1024     // [32]
#define WS_HINGE  1056     // [32]
#define WS_EDGE   1088     // [1]
#define WS_ZERO_N 1089
#define WS_SEL    2048     // int [4*8*512] = 16384
#define WS_EB     20480    // [4*4096*32] = 524288
#define WS_SQ     544768   // [16384]
// total ~2.3 MB of ws

__global__ __launch_bounds__(256) void k_zero(float* __restrict__ ws) {
    int i = blockIdx.x * 256 + threadIdx.x;
    if (i < WS_ZERO_N) ws[i] = 0.f;
}

// Pass 1: segment sums (for means) + counts. 1024 blocks, 1024 px/block (4/thread).
__global__ __launch_bounds__(256) void k_seg_sums(const float* __restrict__ feat,
                                                  const int* __restrict__ lab,
                                                  float* __restrict__ sums,
                                                  float* __restrict__ cnts) {
    __shared__ float srep[8][NI][33];   // 8 replicas, pad 33 -> banks spread
    __shared__ int   crep[8][NI];
    int tid = threadIdx.x;
    int blk = blockIdx.x;
    int b  = blk >> 8;          // 256 blocks per image
    int cb = blk & 255;
    int p0 = cb * 1024 + tid * 4;
    for (int i = tid; i < 8 * NI * 33; i += 256) (&srep[0][0][0])[i] = 0.f;
    if (tid < 64) (&crep[0][0])[tid] = 0;
    __syncthreads();

    int4 l0 = *(const int4*)(lab + (size_t)b * NPIX + p0);
    int lv[4] = {l0.x, l0.y, l0.z, l0.w};
    int rep = tid & 7;
#pragma unroll
    for (int m = 0; m < 4; m++) atomicAdd(&crep[rep][lv[m]], 1);

    const float* fb = feat + (size_t)b * NC * NPIX + p0;
    for (int c = 0; c < NC; c++) {
        float4 v = *(const float4*)(fb + (size_t)c * NPIX);
        float fv[4] = {v.x, v.y, v.z, v.w};
#pragma unroll
        for (int m = 0; m < 4; m++) atomicAdd(&srep[rep][lv[m]][c], fv[m]);
    }
    __syncthreads();
    {   // 256 threads == 8 instances * 32 channels
        int i = tid >> 5, c = tid & 31;
        float s = 0.f;
#pragma unroll
        for (int r = 0; r < 8; r++) s += srep[r][i][c];
        atomicAdd(&sums[(b * NI + i) * NC + c], s);
    }
    if (tid < NI) {
        int s = 0;
#pragma unroll
        for (int r = 0; r < 8; r++) s += crep[r][tid];
        atomicAdd(&cnts[b * NI + tid], (float)s);
    }
}

// Pass 2: per-pixel distance to own mean -> hinge^2, segment-summed.
__global__ __launch_bounds__(256) void k_var(const float* __restrict__ feat,
                                             const int* __restrict__ lab,
                                             const float* __restrict__ sums,
                                             const float* __restrict__ cnts,
                                             float* __restrict__ hinge) {
    __shared__ float mlds[NI][33];
    __shared__ float hrep[8][NI];
    int tid = threadIdx.x;
    int blk = blockIdx.x;
    int b  = blk >> 8;
    int cb = blk & 255;
    int p0 = cb * 1024 + tid * 4;
    {
        int i = tid >> 5, c = tid & 31;
        mlds[i][c] = sums[(b * NI + i) * NC + c] / cnts[b * NI + i];
    }
    if (tid < 64) (&hrep[0][0])[tid] = 0.f;
    __syncthreads();

    int4 l0 = *(const int4*)(lab + (size_t)b * NPIX + p0);
    int lv[4] = {l0.x, l0.y, l0.z, l0.w};
    float acc[4] = {0.f, 0.f, 0.f, 0.f};
    const float* fb = feat + (size_t)b * NC * NPIX + p0;
    for (int c = 0; c < NC; c++) {
        float4 v = *(const float4*)(fb + (size_t)c * NPIX);
        float fv[4] = {v.x, v.y, v.z, v.w};
#pragma unroll
        for (int m = 0; m < 4; m++) {
            float d = fv[m] - mlds[lv[m]][c];
            acc[m] += d * d;
        }
    }
    int rep = tid & 7;
#pragma unroll
    for (int m = 0; m < 4; m++) {
        float d = sqrtf(acc[m] + FEPS);   // acc >= 0 always
        float h = fmaxf(d - 0.5f, 0.f);   // DV = 0.5
        atomicAdd(&hrep[rep][lv[m]], h * h);
    }
    __syncthreads();
    if (tid < NI) {
        float s = 0.f;
#pragma unroll
        for (int r = 0; r < 8; r++) s += hrep[r][tid];
        atomicAdd(&hinge[b * NI + tid], s);
    }
}

// Ordered "first 512 pixels with labelEdges==i" per (b,i). One wave per pair.
__global__ __launch_bounds__(64) void k_sel(const int* __restrict__ le, int* __restrict__ sel) {
    int inst = blockIdx.x & 7;
    int b = blockIdx.x >> 3;
    int lane = threadIdx.x;
    const int* lp = le + (size_t)b * NPIX;
    int* sp = sel + blockIdx.x * NE;
    int s = 0;
    for (int base = 0; base < NPIX && s < NE; base += 256) {
        int4 l = *(const int4*)(lp + base + lane * 4);
        int m0 = (l.x == inst), m1 = (l.y == inst), m2 = (l.z == inst), m3 = (l.w == inst);
        int cnt = m0 + m1 + m2 + m3;
        int incl = cnt;
#pragma unroll
        for (int off = 1; off < 64; off <<= 1) {
            int t = __shfl_up(incl, off);
            if (lane >= off) incl += t;
        }
        int r = incl - cnt;
        int pbase = base + lane * 4;
        if (m0) { if (s + r < NE) sp[s + r] = pbase + 0; r++; }
        if (m1) { if (s + r < NE) sp[s + r] = pbase + 1; r++; }
        if (m2) { if (s + r < NE) sp[s + r] = pbase + 2; r++; }
        if (m3) { if (s + r < NE) sp[s + r] = pbase + 3; r++; }
        s += __shfl(incl, 63);
    }
    for (int idx = s + lane; idx < NE; idx += 64) sp[idx] = 0;  // safety, never expected
}

// Gather edge rows -> contiguous [4][4096][32] + row squared norms.
__global__ __launch_bounds__(256) void k_gather(const float* __restrict__ feat,
                                                const int* __restrict__ sel,
                                                float* __restrict__ eb,
                                                float* __restrict__ sq) {
    int tid = threadIdx.x;
    int rowg = blockIdx.x * 8 + (tid >> 5);
    int c = tid & 31;
    int b = rowg >> 12;
    int p = sel[rowg];
    float v = feat[((size_t)b * NC + c) * NPIX + p];
    eb[(size_t)rowg * NC + c] = v;
    float s = v * v;
#pragma unroll
    for (int off = 16; off > 0; off >>= 1) s += __shfl_xor(s, off);
    if (c == 0) sq[rowg] = s;
}

// Edge pair loss: per (b, pair i<j, 128x128 tile). 8x8 register tiling,
// XOR-swizzled LDS so b128 reads are <=2-way bank aliased (free).
__global__ __launch_bounds__(256) void k_edge(const float* __restrict__ eb,
                                              const float* __restrict__ sq,
                                              float* __restrict__ edge_acc) {
    __shared__ float At[128 * 32];
    __shared__ float Bt[128 * 32];
    __shared__ float sqa[128], sqb[128];
    __shared__ float wsum[4];
    int tid = threadIdx.x;
    int ti = blockIdx.x >> 2, tj = blockIdx.x & 3;
    int q = blockIdx.y;       // 0..27
    int b = blockIdx.z;
    int pi = 0, pj = 0, k = q;
    for (int i = 0; i < 8; i++) { int row = 7 - i; if (k < row) { pi = i; pj = i + 1 + k; break; } k -= row; }
    int base_a = b * 4096 + pi * NE + ti * 128;
    int base_b = b * 4096 + pj * NE + tj * 128;

#pragma unroll
    for (int kk = 0; kk < 16; kk++) {
        int lin = tid + kk * 256;
        int r = lin >> 5, c = lin & 31;
        int sw = r * 32 + ((((c >> 2) ^ (r >> 3)) & 7) << 2) + (c & 3);
        At[sw] = eb[(size_t)(base_a + r) * NC + c];
        Bt[sw] = eb[(size_t)(base_b + r) * NC + c];
    }
    if (tid < 128) sqa[tid] = sq[base_a + tid];
    else if (tid < 256) sqb[tid - 128] = sq[base_b + tid - 128];
    __syncthreads();

    int tx = tid & 15, ty = tid >> 4;
    int r0 = ty * 8, c0 = tx * 8;
    float acc[8][8];
#pragma unroll
    for (int u = 0; u < 8; u++)
#pragma unroll
        for (int v = 0; v < 8; v++) acc[u][v] = 0.f;

#pragma unroll
    for (int cg = 0; cg < 8; cg++) {
        float4 a[8], bb[8];
#pragma unroll
        for (int u = 0; u < 8; u++) {
            int r = r0 + u;
            a[u] = *(const float4*)&At[r * 32 + (((cg ^ (r >> 3)) & 7) << 2)];
        }
#pragma unroll
        for (int v = 0; v < 8; v++) {
            int r = c0 + v;
            bb[v] = *(const float4*)&Bt[r * 32 + (((cg ^ (r >> 3)) & 7) << 2)];
        }
#pragma unroll
        for (int u = 0; u < 8; u++)
#pragma unroll
            for (int v = 0; v < 8; v++) {
                acc[u][v] += a[u].x * bb[v].x + a[u].y * bb[v].y
                           + a[u].z * bb[v].z + a[u].w * bb[v].w;
            }
    }

    float lsum = 0.f;
#pragma unroll
    for (int u = 0; u < 8; u++) {
        float sa = sqa[r0 + u];
#pragma unroll
        for (int v = 0; v < 8; v++) {
            float d2 = sa + sqb[c0 + v] - 2.f * acc[u][v];
            float pd = sqrtf(fmaxf(d2, 0.f) + FEPS);
            float t = 2.f - pd;                  // 2*(DD-DV)
            if (t > 0.f) lsum += t * t;
        }
    }
#pragma unroll
    for (int off = 32; off > 0; off >>= 1) lsum += __shfl_xor(lsum, off);
    if ((tid & 63) == 0) wsum[tid >> 6] = lsum;
    __syncthreads();
    if (tid == 0) atomicAdd(edge_acc, wsum[0] + wsum[1] + wsum[2] + wsum[3]);
}

// Final combine: var, dist, edge, reg, total -> d_out[5]
__global__ __launch_bounds__(256) void k_final(const float* __restrict__ sums,
                                               const float* __restrict__ cnts,
                                               const float* __restrict__ hinge,
                                               const float* __restrict__ edge_acc,
                                               float* __restrict__ out) {
    __shared__ float m[NB * NI * NC];
    __shared__ float accs[3];   // var, dist, reg
    int tid = threadIdx.x;
    if (tid < 3) accs[tid] = 0.f;
    for (int i = tid; i < NB * NI * NC; i += 256) m[i] = sums[i] / cnts[i >> 5];
    __syncthreads();

    float var_p = 0.f, dist_p = 0.f, reg_p = 0.f;
    if (tid < 32) {   // (b, i)
        var_p = hinge[tid] / cnts[tid] * (1.f / 8.f);
        const float* mm = &m[tid * NC];
        float s = 0.f;
        for (int c = 0; c < NC; c++) s += mm[c] * mm[c];
        reg_p = sqrtf(s + FEPS) * (0.001f / 8.f);   // DELTA / N
    }
    if (tid < NB * 28) {
        int b = tid / 28, q = tid % 28;
        int pi = 0, pj = 0, k = q;
        for (int i = 0; i < 8; i++) { int row = 7 - i; if (k < row) { pi = i; pj = i + 1 + k; break; } k -= row; }
        const float* ma = &m[(b * NI + pi) * NC];
        const float* mb = &m[(b * NI + pj) * NC];
        float s = 0.f;
        for (int c = 0; c < NC; c++) { float d = ma[c] - mb[c]; s += d * d; }
        float dm = sqrtf(s + FEPS);
        float t = fmaxf(3.0f - dm, 0.f);   // 2*DD - dm
        dist_p = t * t * (1.f / 56.f);
    }
    atomicAdd(&accs[0], var_p);
    atomicAdd(&accs[1], dist_p);
    atomicAdd(&accs[2], reg_p);
    __syncthreads();
    if (tid == 0) {
        float var = accs[0], dist = accs[1], reg = accs[2];
        float edge = edge_acc[0] * (1.f / (512.f * 512.f * 56.f));
        out[0] = var + dist + edge + reg;
        out[1] = var;
        out[2] = dist;
        out[3] = edge;
        out[4] = reg;
    }
}

extern "C" void kernel_launch(void* const* d_in, const int* in_sizes, int n_in,
                              void* d_out, int out_size, void* d_ws, size_t ws_size,
                              hipStream_t stream) {
    const float* feat   = (const float*)d_in[0];
    const int*   labels = (const int*)d_in[1];
    const int*   le     = (const int*)d_in[2];
    float* out = (float*)d_out;
    float* ws  = (float*)d_ws;

    float* sums  = ws + WS_SUMS;
    float* cnts  = ws + WS_CNT;
    float* hinge = ws + WS_HINGE;
    float* edge  = ws + WS_EDGE;
    int*   sel   = (int*)(ws + WS_SEL);
    float* eb    = ws + WS_EB;
    float* sq    = ws + WS_SQ;

    hipLaunchKernelGGL(k_zero,     dim3(5),           dim3(256), 0, stream, ws);
    hipLaunchKernelGGL(k_seg_sums, dim3(1024),        dim3(256), 0, stream, feat, labels, sums, cnts);
    hipLaunchKernelGGL(k_var,      dim3(1024),        dim3(256), 0, stream, feat, labels, sums, cnts, hinge);
    hipLaunchKernelGGL(k_sel,      dim3(32),          dim3(64),  0, stream, le, sel);
    hipLaunchKernelGGL(k_gather,   dim3(2048),        dim3(256), 0, stream, feat, sel, eb, sq);
    hipLaunchKernelGGL(k_edge,     dim3(16, 28, 4),   dim3(256), 0, stream, eb, sq, edge);
    hipLaunchKernelGGL(k_final,    dim3(1),           dim3(256), 0, stream, sums, cnts, hinge, edge, out);
}

// Round 2
// 369.377 us; speedup vs baseline: 1.2578x; 1.2578x over previous
//
#include <hip/hip_runtime.h>

// Problem constants
#define NB 4
#define NC 32
#define NPIX 262144   // 512*512
#define NI 8
#define NE 512
#define FEPS 1e-12f

// Workspace layout (float offsets)
#define WS_SUMS   0        // [4][8][32] = 1024
#define WS_CNT    1024     // [32]
#define WS_HINGE  1056     // [32]
#define WS_EDGE   1088     // [1]
#define WS_ZERO_N 1089
#define WS_SEL    2048     // int [4*8*512] = 16384
#define WS_EB     20480    // [4*4096*32] = 524288
#define WS_SQ     544768   // [16384]

__global__ __launch_bounds__(256) void k_zero(float* __restrict__ ws) {
    int i = blockIdx.x * 256 + threadIdx.x;
    if (i < WS_ZERO_N) ws[i] = 0.f;
}

// Pass 1: segment sums + counts. Register accumulation, no LDS atomics.
// 1024 blocks x 256 thr. Block: image b, 1024-px chunk. Wave w: channels [8w,8w+8).
__global__ __launch_bounds__(256, 2) void k_seg_sums(const float* __restrict__ feat,
                                                     const int* __restrict__ lab,
                                                     float* __restrict__ sums,
                                                     float* __restrict__ cnts) {
    int tid = threadIdx.x;
    int lane = tid & 63, w = tid >> 6;
    int b = blockIdx.x >> 8, cb = blockIdx.x & 255;
    const float* fb = feat + ((size_t)b * NC + w * 8) * NPIX + cb * 1024;
    const int*   lb = lab + (size_t)b * NPIX + cb * 1024;

    float r[64];
#pragma unroll
    for (int k = 0; k < 64; k++) r[k] = 0.f;
    float cnt[8] = {0.f, 0.f, 0.f, 0.f, 0.f, 0.f, 0.f, 0.f};

#pragma unroll 1
    for (int g = 0; g < 4; g++) {
        int idx = g * 256 + lane * 4;
        int4 lv = *(const int4*)(lb + idx);
        float4 msk[8];
#pragma unroll
        for (int bin = 0; bin < 8; bin++) {
            msk[bin].x = (lv.x == bin) ? 1.f : 0.f;
            msk[bin].y = (lv.y == bin) ? 1.f : 0.f;
            msk[bin].z = (lv.z == bin) ? 1.f : 0.f;
            msk[bin].w = (lv.w == bin) ? 1.f : 0.f;
        }
        if (w == 0) {
#pragma unroll
            for (int bin = 0; bin < 8; bin++)
                cnt[bin] += msk[bin].x + msk[bin].y + msk[bin].z + msk[bin].w;
        }
#pragma unroll
        for (int c = 0; c < 8; c++) {
            float4 f = *(const float4*)(fb + (size_t)c * NPIX + idx);
#pragma unroll
            for (int bin = 0; bin < 8; bin++)
                r[c * 8 + bin] += msk[bin].x * f.x + msk[bin].y * f.y
                                + msk[bin].z * f.z + msk[bin].w * f.w;
        }
    }

    // Recursive-halving fold: lane L ends with sum over all 64 lanes of r[L].
    // All register indices compile-time (no scratch spill).
#pragma unroll
    for (int half = 32; half >= 1; half >>= 1) {
#pragma unroll
        for (int k = 0; k < half; k++) {
            float t0 = __shfl_xor(r[k], half);
            float t1 = __shfl_xor(r[k + half], half);
            r[k] = (lane & half) ? (r[k + half] + t1) : (r[k] + t0);
        }
    }
    // lane L -> bin = L&7, c' = L>>3  (r index was c'*8+bin)
    atomicAdd(&sums[((size_t)b * NI + (lane & 7)) * NC + w * 8 + (lane >> 3)], r[0]);

    if (w == 0) {
        // reduce cnt[8] over 64 lanes: butterfly across 8-lane classes, then fold
#pragma unroll
        for (int m = 8; m <= 32; m <<= 1) {
#pragma unroll
            for (int bin = 0; bin < 8; bin++) cnt[bin] += __shfl_xor(cnt[bin], m);
        }
#pragma unroll
        for (int half = 4; half >= 1; half >>= 1) {
#pragma unroll
            for (int k = 0; k < half; k++) {
                float t0 = __shfl_xor(cnt[k], half);
                float t1 = __shfl_xor(cnt[k + half], half);
                cnt[k] = (lane & half) ? (cnt[k + half] + t1) : (cnt[k] + t0);
            }
        }
        if (lane < 8) atomicAdd(&cnts[b * NI + lane], cnt[0]);
    }
}

// Pass 2: per-pixel ||f - mu_lab||, hinge^2, binned. 8 loads in flight.
__global__ __launch_bounds__(256, 4) void k_var(const float* __restrict__ feat,
                                                const int* __restrict__ lab,
                                                const float* __restrict__ sums,
                                                const float* __restrict__ cnts,
                                                float* __restrict__ hinge) {
    __shared__ float mlds[NI][33];
    __shared__ float hred[4][8];
    int tid = threadIdx.x;
    int lane = tid & 63, w = tid >> 6;
    int b = blockIdx.x >> 8, cb = blockIdx.x & 255;
    {
        int i = tid >> 5, c = tid & 31;
        mlds[i][c] = sums[(b * NI + i) * NC + c] / cnts[b * NI + i];
    }
    __syncthreads();

    int idx = tid * 4;
    int4 lv = *(const int4*)(lab + (size_t)b * NPIX + cb * 1024 + idx);
    const float* fb = feat + (size_t)b * NC * NPIX + cb * 1024 + idx;
    float ax = 0.f, ay = 0.f, az = 0.f, aw = 0.f;
#pragma unroll 1
    for (int cc = 0; cc < NC; cc += 8) {
        float4 f[8];
#pragma unroll
        for (int u = 0; u < 8; u++) f[u] = *(const float4*)(fb + (size_t)(cc + u) * NPIX);
#pragma unroll
        for (int u = 0; u < 8; u++) {
            int c = cc + u;
            float d;
            d = f[u].x - mlds[lv.x][c]; ax += d * d;
            d = f[u].y - mlds[lv.y][c]; ay += d * d;
            d = f[u].z - mlds[lv.z][c]; az += d * d;
            d = f[u].w - mlds[lv.w][c]; aw += d * d;
        }
    }
    float t;
    t = fmaxf(sqrtf(ax + FEPS) - 0.5f, 0.f); float hx = t * t;
    t = fmaxf(sqrtf(ay + FEPS) - 0.5f, 0.f); float hy = t * t;
    t = fmaxf(sqrtf(az + FEPS) - 0.5f, 0.f); float hz = t * t;
    t = fmaxf(sqrtf(aw + FEPS) - 0.5f, 0.f); float hw = t * t;

    float hacc[8];
#pragma unroll
    for (int bin = 0; bin < 8; bin++)
        hacc[bin] = ((lv.x == bin) ? hx : 0.f) + ((lv.y == bin) ? hy : 0.f)
                  + ((lv.z == bin) ? hz : 0.f) + ((lv.w == bin) ? hw : 0.f);
#pragma unroll
    for (int m = 8; m <= 32; m <<= 1) {
#pragma unroll
        for (int bin = 0; bin < 8; bin++) hacc[bin] += __shfl_xor(hacc[bin], m);
    }
#pragma unroll
    for (int half = 4; half >= 1; half >>= 1) {
#pragma unroll
        for (int k = 0; k < half; k++) {
            float t0 = __shfl_xor(hacc[k], half);
            float t1 = __shfl_xor(hacc[k + half], half);
            hacc[k] = (lane & half) ? (hacc[k + half] + t1) : (hacc[k] + t0);
        }
    }
    if (lane < 8) hred[w][lane] = hacc[0];
    __syncthreads();
    if (tid < 8)
        atomicAdd(&hinge[b * NI + tid],
                  hred[0][tid] + hred[1][tid] + hred[2][tid] + hred[3][tid]);
}

// Ordered "first 512 pixels with labelEdges==i" per (b,i). One wave per pair.
__global__ __launch_bounds__(64) void k_sel(const int* __restrict__ le, int* __restrict__ sel) {
    int inst = blockIdx.x & 7;
    int b = blockIdx.x >> 3;
    int lane = threadIdx.x;
    const int* lp = le + (size_t)b * NPIX;
    int* sp = sel + blockIdx.x * NE;
    int s = 0;
    for (int base = 0; base < NPIX && s < NE; base += 256) {
        int4 l = *(const int4*)(lp + base + lane * 4);
        int m0 = (l.x == inst), m1 = (l.y == inst), m2 = (l.z == inst), m3 = (l.w == inst);
        int cnt = m0 + m1 + m2 + m3;
        int incl = cnt;
#pragma unroll
        for (int off = 1; off < 64; off <<= 1) {
            int t = __shfl_up(incl, off);
            if (lane >= off) incl += t;
        }
        int r = incl - cnt;
        int pbase = base + lane * 4;
        if (m0) { if (s + r < NE) sp[s + r] = pbase + 0; r++; }
        if (m1) { if (s + r < NE) sp[s + r] = pbase + 1; r++; }
        if (m2) { if (s + r < NE) sp[s + r] = pbase + 2; r++; }
        if (m3) { if (s + r < NE) sp[s + r] = pbase + 3; r++; }
        s += __shfl(incl, 63);
    }
    for (int idx = s + lane; idx < NE; idx += 64) sp[idx] = 0;  // safety, never expected
}

// Gather edge rows -> [4*8*512][32] + row squared norms. Lanes index rows
// (sel is ascending -> locality); channels in the inner loop.
__global__ __launch_bounds__(256) void k_gather(const float* __restrict__ feat,
                                                const int* __restrict__ sel,
                                                float* __restrict__ eb,
                                                float* __restrict__ sq) {
    int bi = blockIdx.x;          // 0..31 = b*8+i
    int b = bi >> 3;
    int tid = threadIdx.x;
    int r0 = bi * NE + tid;
    int r1 = r0 + 256;
    int p0 = sel[r0], p1 = sel[r1];
    const float* fp = feat + (size_t)b * NC * NPIX;
    float s0 = 0.f, s1 = 0.f;
#pragma unroll
    for (int c = 0; c < NC; c++) {
        float v0 = fp[(size_t)c * NPIX + p0];
        float v1 = fp[(size_t)c * NPIX + p1];
        eb[(size_t)r0 * NC + c] = v0;
        eb[(size_t)r1 * NC + c] = v1;
        s0 += v0 * v0;
        s1 += v1 * v1;
    }
    sq[r0] = s0;
    sq[r1] = s1;
}

// Edge pair loss: per (b, pair i<j, 128x128 tile). 8x8 register tiling,
// XOR-swizzled LDS so b128 reads are <=2-way bank aliased (free).
__global__ __launch_bounds__(256) void k_edge(const float* __restrict__ eb,
                                              const float* __restrict__ sq,
                                              float* __restrict__ edge_acc) {
    __shared__ float At[128 * 32];
    __shared__ float Bt[128 * 32];
    __shared__ float sqa[128], sqb[128];
    __shared__ float wsum[4];
    int tid = threadIdx.x;
    int ti = blockIdx.x >> 2, tj = blockIdx.x & 3;
    int q = blockIdx.y;       // 0..27
    int b = blockIdx.z;
    int pi = 0, pj = 0, k = q;
    for (int i = 0; i < 8; i++) { int row = 7 - i; if (k < row) { pi = i; pj = i + 1 + k; break; } k -= row; }
    int base_a = b * 4096 + pi * NE + ti * 128;
    int base_b = b * 4096 + pj * NE + tj * 128;

#pragma unroll
    for (int kk = 0; kk < 16; kk++) {
        int lin = tid + kk * 256;
        int r = lin >> 5, c = lin & 31;
        int sw = r * 32 + ((((c >> 2) ^ (r >> 3)) & 7) << 2) + (c & 3);
        At[sw] = eb[(size_t)(base_a + r) * NC + c];
        Bt[sw] = eb[(size_t)(base_b + r) * NC + c];
    }
    if (tid < 128) sqa[tid] = sq[base_a + tid];
    else if (tid < 256) sqb[tid - 128] = sq[base_b + tid - 128];
    __syncthreads();

    int tx = tid & 15, ty = tid >> 4;
    int r0 = ty * 8, c0 = tx * 8;
    float acc[8][8];
#pragma unroll
    for (int u = 0; u < 8; u++)
#pragma unroll
        for (int v = 0; v < 8; v++) acc[u][v] = 0.f;

#pragma unroll
    for (int cg = 0; cg < 8; cg++) {
        float4 a[8], bb[8];
#pragma unroll
        for (int u = 0; u < 8; u++) {
            int r = r0 + u;
            a[u] = *(const float4*)&At[r * 32 + (((cg ^ (r >> 3)) & 7) << 2)];
        }
#pragma unroll
        for (int v = 0; v < 8; v++) {
            int r = c0 + v;
            bb[v] = *(const float4*)&Bt[r * 32 + (((cg ^ (r >> 3)) & 7) << 2)];
        }
#pragma unroll
        for (int u = 0; u < 8; u++)
#pragma unroll
            for (int v = 0; v < 8; v++) {
                acc[u][v] += a[u].x * bb[v].x + a[u].y * bb[v].y
                           + a[u].z * bb[v].z + a[u].w * bb[v].w;
            }
    }

    float lsum = 0.f;
#pragma unroll
    for (int u = 0; u < 8; u++) {
        float sa = sqa[r0 + u];
#pragma unroll
        for (int v = 0; v < 8; v++) {
            float d2 = sa + sqb[c0 + v] - 2.f * acc[u][v];
            float pd = sqrtf(fmaxf(d2, 0.f) + FEPS);
            float t = 2.f - pd;                  // 2*(DD-DV)
            if (t > 0.f) lsum += t * t;
        }
    }
#pragma unroll
    for (int off = 32; off > 0; off >>= 1) lsum += __shfl_xor(lsum, off);
    if ((tid & 63) == 0) wsum[tid >> 6] = lsum;
    __syncthreads();
    if (tid == 0) atomicAdd(edge_acc, wsum[0] + wsum[1] + wsum[2] + wsum[3]);
}

// Final combine: var, dist, edge, reg, total -> d_out[5]
__global__ __launch_bounds__(256) void k_final(const float* __restrict__ sums,
                                               const float* __restrict__ cnts,
                                               const float* __restrict__ hinge,
                                               const float* __restrict__ edge_acc,
                                               float* __restrict__ out) {
    __shared__ float m[NB * NI * NC];
    __shared__ float accs[3];   // var, dist, reg
    int tid = threadIdx.x;
    if (tid < 3) accs[tid] = 0.f;
    for (int i = tid; i < NB * NI * NC; i += 256) m[i] = sums[i] / cnts[i >> 5];
    __syncthreads();

    float var_p = 0.f, dist_p = 0.f, reg_p = 0.f;
    if (tid < 32) {   // (b, i)
        var_p = hinge[tid] / cnts[tid] * (1.f / 8.f);
        const float* mm = &m[tid * NC];
        float s = 0.f;
        for (int c = 0; c < NC; c++) s += mm[c] * mm[c];
        reg_p = sqrtf(s + FEPS) * (0.001f / 8.f);   // DELTA / N
    }
    if (tid < NB * 28) {
        int b = tid / 28, q = tid % 28;
        int pi = 0, pj = 0, k = q;
        for (int i = 0; i < 8; i++) { int row = 7 - i; if (k < row) { pi = i; pj = i + 1 + k; break; } k -= row; }
        const float* ma = &m[(b * NI + pi) * NC];
        const float* mb = &m[(b * NI + pj) * NC];
        float s = 0.f;
        for (int c = 0; c < NC; c++) { float d = ma[c] - mb[c]; s += d * d; }
        float dm = sqrtf(s + FEPS);
        float t = fmaxf(3.0f - dm, 0.f);   // 2*DD - dm
        dist_p = t * t * (1.f / 56.f);
    }
    atomicAdd(&accs[0], var_p);
    atomicAdd(&accs[1], dist_p);
    atomicAdd(&accs[2], reg_p);
    __syncthreads();
    if (tid == 0) {
        float var = accs[0], dist = accs[1], reg = accs[2];
        float edge = edge_acc[0] * (1.f / (512.f * 512.f * 56.f));
        out[0] = var + dist + edge + reg;
        out[1] = var;
        out[2] = dist;
        out[3] = edge;
        out[4] = reg;
    }
}

extern "C" void kernel_launch(void* const* d_in, const int* in_sizes, int n_in,
                              void* d_out, int out_size, void* d_ws, size_t ws_size,
                              hipStream_t stream) {
    const float* feat   = (const float*)d_in[0];
    const int*   labels = (const int*)d_in[1];
    const int*   le     = (const int*)d_in[2];
    float* out = (float*)d_out;
    float* ws  = (float*)d_ws;

    float* sums  = ws + WS_SUMS;
    float* cnts  = ws + WS_CNT;
    float* hinge = ws + WS_HINGE;
    float* edge  = ws + WS_EDGE;
    int*   sel   = (int*)(ws + WS_SEL);
    float* eb    = ws + WS_EB;
    float* sq    = ws + WS_SQ;

    hipLaunchKernelGGL(k_zero,     dim3(5),           dim3(256), 0, stream, ws);
    hipLaunchKernelGGL(k_seg_sums, dim3(1024),        dim3(256), 0, stream, feat, labels, sums, cnts);
    hipLaunchKernelGGL(k_var,      dim3(1024),        dim3(256), 0, stream, feat, labels, sums, cnts, hinge);
    hipLaunchKernelGGL(k_sel,      dim3(32),          dim3(64),  0, stream, le, sel);
    hipLaunchKernelGGL(k_gather,   dim3(32),          dim3(256), 0, stream, feat, sel, eb, sq);
    hipLaunchKernelGGL(k_edge,     dim3(16, 28, 4),   dim3(256), 0, stream, eb, sq, edge);
    hipLaunchKernelGGL(k_final,    dim3(1),           dim3(256), 0, stream, sums, cnts, hinge, edge, out);
}

// Round 3
// 309.911 us; speedup vs baseline: 1.4992x; 1.1919x over previous
//
#include <hip/hip_runtime.h>

// Problem constants
#define NB 4
#define NC 32
#define NPIX 262144   // 512*512
#define NI 8
#define NE 512
#define FEPS 1e-12f

// Workspace layout (float offsets)
#define WS_SUMS   0        // [4][8][32] = 1024
#define WS_CNT    1024     // [32]
#define WS_HINGE  1056     // [32]
#define WS_EDGE   1088     // [1]
#define WS_ZERO_N 1089
#define WS_SEL    2048     // int [4*8*512] = 16384
#define WS_EB     20480    // bf16 [4*4096*32] = 524288 shorts = 262144 floats
#define WS_SQ     544768   // [16384]

typedef __bf16 bf16x8 __attribute__((ext_vector_type(8)));
typedef float  f32x4  __attribute__((ext_vector_type(4)));

static __device__ __forceinline__ unsigned short f2bf(float x) {
    unsigned u = __builtin_bit_cast(unsigned, x);
    u += 0x7FFF + ((u >> 16) & 1);          // RNE
    return (unsigned short)(u >> 16);
}

__global__ __launch_bounds__(256) void k_zero(float* __restrict__ ws) {
    int i = blockIdx.x * 256 + threadIdx.x;
    if (i < WS_ZERO_N) ws[i] = 0.f;
}

// Pass 1: segment sums + counts. Register accumulation, no LDS atomics.
__global__ __launch_bounds__(256, 2) void k_seg_sums(const float* __restrict__ feat,
                                                     const int* __restrict__ lab,
                                                     float* __restrict__ sums,
                                                     float* __restrict__ cnts) {
    int tid = threadIdx.x;
    int lane = tid & 63, w = tid >> 6;
    int b = blockIdx.x >> 8, cb = blockIdx.x & 255;
    const float* fb = feat + ((size_t)b * NC + w * 8) * NPIX + cb * 1024;
    const int*   lb = lab + (size_t)b * NPIX + cb * 1024;

    float r[64];
#pragma unroll
    for (int k = 0; k < 64; k++) r[k] = 0.f;
    float cnt[8] = {0.f, 0.f, 0.f, 0.f, 0.f, 0.f, 0.f, 0.f};

#pragma unroll 1
    for (int g = 0; g < 4; g++) {
        int idx = g * 256 + lane * 4;
        int4 lv = *(const int4*)(lb + idx);
        float4 msk[8];
#pragma unroll
        for (int bin = 0; bin < 8; bin++) {
            msk[bin].x = (lv.x == bin) ? 1.f : 0.f;
            msk[bin].y = (lv.y == bin) ? 1.f : 0.f;
            msk[bin].z = (lv.z == bin) ? 1.f : 0.f;
            msk[bin].w = (lv.w == bin) ? 1.f : 0.f;
        }
        if (w == 0) {
#pragma unroll
            for (int bin = 0; bin < 8; bin++)
                cnt[bin] += msk[bin].x + msk[bin].y + msk[bin].z + msk[bin].w;
        }
#pragma unroll
        for (int c = 0; c < 8; c++) {
            float4 f = *(const float4*)(fb + (size_t)c * NPIX + idx);
#pragma unroll
            for (int bin = 0; bin < 8; bin++)
                r[c * 8 + bin] += msk[bin].x * f.x + msk[bin].y * f.y
                                + msk[bin].z * f.z + msk[bin].w * f.w;
        }
    }

#pragma unroll
    for (int half = 32; half >= 1; half >>= 1) {
#pragma unroll
        for (int k = 0; k < half; k++) {
            float t0 = __shfl_xor(r[k], half);
            float t1 = __shfl_xor(r[k + half], half);
            r[k] = (lane & half) ? (r[k + half] + t1) : (r[k] + t0);
        }
    }
    atomicAdd(&sums[((size_t)b * NI + (lane & 7)) * NC + w * 8 + (lane >> 3)], r[0]);

    if (w == 0) {
#pragma unroll
        for (int m = 8; m <= 32; m <<= 1) {
#pragma unroll
            for (int bin = 0; bin < 8; bin++) cnt[bin] += __shfl_xor(cnt[bin], m);
        }
#pragma unroll
        for (int half = 4; half >= 1; half >>= 1) {
#pragma unroll
            for (int k = 0; k < half; k++) {
                float t0 = __shfl_xor(cnt[k], half);
                float t1 = __shfl_xor(cnt[k + half], half);
                cnt[k] = (lane & half) ? (cnt[k + half] + t1) : (cnt[k] + t0);
            }
        }
        if (lane < 8) atomicAdd(&cnts[b * NI + lane], cnt[0]);
    }
}

// Pass 2: per-pixel ||f - mu_lab||, hinge^2, binned. 8 loads in flight.
__global__ __launch_bounds__(256, 4) void k_var(const float* __restrict__ feat,
                                                const int* __restrict__ lab,
                                                const float* __restrict__ sums,
                                                const float* __restrict__ cnts,
                                                float* __restrict__ hinge) {
    __shared__ float mlds[NI][33];
    __shared__ float hred[4][8];
    int tid = threadIdx.x;
    int lane = tid & 63, w = tid >> 6;
    int b = blockIdx.x >> 8, cb = blockIdx.x & 255;
    {
        int i = tid >> 5, c = tid & 31;
        mlds[i][c] = sums[(b * NI + i) * NC + c] / cnts[b * NI + i];
    }
    __syncthreads();

    int idx = tid * 4;
    int4 lv = *(const int4*)(lab + (size_t)b * NPIX + cb * 1024 + idx);
    const float* fb = feat + (size_t)b * NC * NPIX + cb * 1024 + idx;
    float ax = 0.f, ay = 0.f, az = 0.f, aw = 0.f;
#pragma unroll 1
    for (int cc = 0; cc < NC; cc += 8) {
        float4 f[8];
#pragma unroll
        for (int u = 0; u < 8; u++) f[u] = *(const float4*)(fb + (size_t)(cc + u) * NPIX);
#pragma unroll
        for (int u = 0; u < 8; u++) {
            int c = cc + u;
            float d;
            d = f[u].x - mlds[lv.x][c]; ax += d * d;
            d = f[u].y - mlds[lv.y][c]; ay += d * d;
            d = f[u].z - mlds[lv.z][c]; az += d * d;
            d = f[u].w - mlds[lv.w][c]; aw += d * d;
        }
    }
    float t;
    t = fmaxf(sqrtf(ax + FEPS) - 0.5f, 0.f); float hx = t * t;
    t = fmaxf(sqrtf(ay + FEPS) - 0.5f, 0.f); float hy = t * t;
    t = fmaxf(sqrtf(az + FEPS) - 0.5f, 0.f); float hz = t * t;
    t = fmaxf(sqrtf(aw + FEPS) - 0.5f, 0.f); float hw = t * t;

    float hacc[8];
#pragma unroll
    for (int bin = 0; bin < 8; bin++)
        hacc[bin] = ((lv.x == bin) ? hx : 0.f) + ((lv.y == bin) ? hy : 0.f)
                  + ((lv.z == bin) ? hz : 0.f) + ((lv.w == bin) ? hw : 0.f);
#pragma unroll
    for (int m = 8; m <= 32; m <<= 1) {
#pragma unroll
        for (int bin = 0; bin < 8; bin++) hacc[bin] += __shfl_xor(hacc[bin], m);
    }
#pragma unroll
    for (int half = 4; half >= 1; half >>= 1) {
#pragma unroll
        for (int k = 0; k < half; k++) {
            float t0 = __shfl_xor(hacc[k], half);
            float t1 = __shfl_xor(hacc[k + half], half);
            hacc[k] = (lane & half) ? (hacc[k + half] + t1) : (hacc[k] + t0);
        }
    }
    if (lane < 8) hred[w][lane] = hacc[0];
    __syncthreads();
    if (tid < 8)
        atomicAdd(&hinge[b * NI + tid],
                  hred[0][tid] + hred[1][tid] + hred[2][tid] + hred[3][tid]);
}

// Ordered "first 512 pixels with labelEdges==i" per (b,i). One wave per pair.
__global__ __launch_bounds__(64) void k_sel(const int* __restrict__ le, int* __restrict__ sel) {
    int inst = blockIdx.x & 7;
    int b = blockIdx.x >> 3;
    int lane = threadIdx.x;
    const int* lp = le + (size_t)b * NPIX;
    int* sp = sel + blockIdx.x * NE;
    int s = 0;
    for (int base = 0; base < NPIX && s < NE; base += 256) {
        int4 l = *(const int4*)(lp + base + lane * 4);
        int m0 = (l.x == inst), m1 = (l.y == inst), m2 = (l.z == inst), m3 = (l.w == inst);
        int cnt = m0 + m1 + m2 + m3;
        int incl = cnt;
#pragma unroll
        for (int off = 1; off < 64; off <<= 1) {
            int t = __shfl_up(incl, off);
            if (lane >= off) incl += t;
        }
        int r = incl - cnt;
        int pbase = base + lane * 4;
        if (m0) { if (s + r < NE) sp[s + r] = pbase + 0; r++; }
        if (m1) { if (s + r < NE) sp[s + r] = pbase + 1; r++; }
        if (m2) { if (s + r < NE) sp[s + r] = pbase + 2; r++; }
        if (m3) { if (s + r < NE) sp[s + r] = pbase + 3; r++; }
        s += __shfl(incl, 63);
    }
    for (int idx = s + lane; idx < NE; idx += 64) sp[idx] = 0;  // safety, never expected
}

// Gather edge rows -> bf16 [4*8*512][32] (MFMA-friendly row-major) + f32 sq norms.
__global__ __launch_bounds__(256) void k_gather(const float* __restrict__ feat,
                                                const int* __restrict__ sel,
                                                short* __restrict__ ebh,
                                                float* __restrict__ sq) {
    int bi = blockIdx.x;          // 0..31 = b*8+i
    int b = bi >> 3;
    int tid = threadIdx.x;
#pragma unroll
    for (int half = 0; half < 2; half++) {
        int r = bi * NE + half * 256 + tid;
        int p = sel[r];
        const float* fp = feat + (size_t)b * NC * NPIX + p;
        float s = 0.f;
        int pk[16];
#pragma unroll
        for (int c2 = 0; c2 < 16; c2++) {
            float v0 = fp[(size_t)(2 * c2) * NPIX];
            float v1 = fp[(size_t)(2 * c2 + 1) * NPIX];
            s += v0 * v0 + v1 * v1;
            pk[c2] = (unsigned)f2bf(v0) | ((unsigned)f2bf(v1) << 16);
        }
        sq[r] = s;
        int4* dst = (int4*)(ebh + (size_t)r * NC);
        dst[0] = make_int4(pk[0], pk[1], pk[2], pk[3]);
        dst[1] = make_int4(pk[4], pk[5], pk[6], pk[7]);
        dst[2] = make_int4(pk[8], pk[9], pk[10], pk[11]);
        dst[3] = make_int4(pk[12], pk[13], pk[14], pk[15]);
    }
}

// Edge pair loss via MFMA. Block = (b, pair, 128x128 tile); 4 waves.
// Wave w: rows [w*32, w*32+32) of the tile = 2 row-tiles x 8 col-tiles,
// one mfma_f32_16x16x32_bf16 per 16x16 tile (K=32=NC, no K-loop).
// Fragments load straight from global (eb is 1MB -> L2-resident); no LDS tile.
__global__ __launch_bounds__(256) void k_edge(const short* __restrict__ ebh,
                                              const float* __restrict__ sq,
                                              float* __restrict__ edge_acc) {
    __shared__ float sqa[128], sqb[128];
    __shared__ float wsum[4];
    int tid = threadIdx.x;
    int lane = tid & 63, w = tid >> 6;
    int ti = blockIdx.x >> 2, tj = blockIdx.x & 3;
    int q = blockIdx.y;       // 0..27
    int b = blockIdx.z;
    int pi = 0, pj = 0, k = q;
    for (int i = 0; i < 8; i++) { int row = 7 - i; if (k < row) { pi = i; pj = i + 1 + k; break; } k -= row; }
    int base_a = b * 4096 + pi * NE + ti * 128;
    int base_b = b * 4096 + pj * NE + tj * 128;

    if (tid < 128) sqa[tid] = sq[base_a + tid];
    else sqb[tid - 128] = sq[base_b + tid - 128];
    __syncthreads();

    // A/B fragment layout (16x16x32 bf16): lane holds row=lane&15,
    // k=(lane>>4)*8 .. +8 -> one 16B contiguous load per fragment.
    int lrow = lane & 15;
    int lk = (lane >> 4) * 8;

    bf16x8 a[2];
#pragma unroll
    for (int u = 0; u < 2; u++)
        a[u] = *(const bf16x8*)(ebh + (size_t)(base_a + w * 32 + u * 16 + lrow) * NC + lk);
    bf16x8 bb[8];
#pragma unroll
    for (int v = 0; v < 8; v++)
        bb[v] = *(const bf16x8*)(ebh + (size_t)(base_b + v * 16 + lrow) * NC + lk);

    f32x4 acc[2][8];
#pragma unroll
    for (int u = 0; u < 2; u++)
#pragma unroll
        for (int v = 0; v < 8; v++) acc[u][v] = (f32x4){0.f, 0.f, 0.f, 0.f};

#pragma unroll
    for (int u = 0; u < 2; u++)
#pragma unroll
        for (int v = 0; v < 8; v++)
            acc[u][v] = __builtin_amdgcn_mfma_f32_16x16x32_bf16(a[u], bb[v], acc[u][v], 0, 0, 0);

    // C/D layout [m89]: col=lane&15, row=(lane>>4)*4+reg
    float lsum = 0.f;
    int orow0 = w * 32 + (lane >> 4) * 4;
    int ocol = lane & 15;
#pragma unroll
    for (int u = 0; u < 2; u++) {
#pragma unroll
        for (int v = 0; v < 8; v++) {
            float sb = sqb[v * 16 + ocol];
#pragma unroll
            for (int rg = 0; rg < 4; rg++) {
                float d2 = sqa[orow0 + u * 16 + rg] + sb - 2.f * acc[u][v][rg];
                float pd = sqrtf(fmaxf(d2, 0.f) + FEPS);
                float t = 2.f - pd;                  // 2*(DD-DV)
                if (t > 0.f) lsum += t * t;
            }
        }
    }
#pragma unroll
    for (int off = 32; off > 0; off >>= 1) lsum += __shfl_xor(lsum, off);
    if (lane == 0) wsum[w] = lsum;
    __syncthreads();
    if (tid == 0) atomicAdd(edge_acc, wsum[0] + wsum[1] + wsum[2] + wsum[3]);
}

// Final combine: var, dist, edge, reg, total -> d_out[5]
__global__ __launch_bounds__(256) void k_final(const float* __restrict__ sums,
                                               const float* __restrict__ cnts,
                                               const float* __restrict__ hinge,
                                               const float* __restrict__ edge_acc,
                                               float* __restrict__ out) {
    __shared__ float m[NB * NI * NC];
    __shared__ float accs[3];   // var, dist, reg
    int tid = threadIdx.x;
    if (tid < 3) accs[tid] = 0.f;
    for (int i = tid; i < NB * NI * NC; i += 256) m[i] = sums[i] / cnts[i >> 5];
    __syncthreads();

    float var_p = 0.f, dist_p = 0.f, reg_p = 0.f;
    if (tid < 32) {   // (b, i)
        var_p = hinge[tid] / cnts[tid] * (1.f / 8.f);
        const float* mm = &m[tid * NC];
        float s = 0.f;
        for (int c = 0; c < NC; c++) s += mm[c] * mm[c];
        reg_p = sqrtf(s + FEPS) * (0.001f / 8.f);   // DELTA / N
    }
    if (tid < NB * 28) {
        int b = tid / 28, q = tid % 28;
        int pi = 0, pj = 0, k = q;
        for (int i = 0; i < 8; i++) { int row = 7 - i; if (k < row) { pi = i; pj = i + 1 + k; break; } k -= row; }
        const float* ma = &m[(b * NI + pi) * NC];
        const float* mb = &m[(b * NI + pj) * NC];
        float s = 0.f;
        for (int c = 0; c < NC; c++) { float d = ma[c] - mb[c]; s += d * d; }
        float dm = sqrtf(s + FEPS);
        float t = fmaxf(3.0f - dm, 0.f);   // 2*DD - dm
        dist_p = t * t * (1.f / 56.f);
    }
    atomicAdd(&accs[0], var_p);
    atomicAdd(&accs[1], dist_p);
    atomicAdd(&accs[2], reg_p);
    __syncthreads();
    if (tid == 0) {
        float var = accs[0], dist = accs[1], reg = accs[2];
        float edge = edge_acc[0] * (1.f / (512.f * 512.f * 56.f));
        out[0] = var + dist + edge + reg;
        out[1] = var;
        out[2] = dist;
        out[3] = edge;
        out[4] = reg;
    }
}

extern "C" void kernel_launch(void* const* d_in, const int* in_sizes, int n_in,
                              void* d_out, int out_size, void* d_ws, size_t ws_size,
                              hipStream_t stream) {
    const float* feat   = (const float*)d_in[0];
    const int*   labels = (const int*)d_in[1];
    const int*   le     = (const int*)d_in[2];
    float* out = (float*)d_out;
    float* ws  = (float*)d_ws;

    float* sums  = ws + WS_SUMS;
    float* cnts  = ws + WS_CNT;
    float* hinge = ws + WS_HINGE;
    float* edge  = ws + WS_EDGE;
    int*   sel   = (int*)(ws + WS_SEL);
    short* ebh   = (short*)(ws + WS_EB);
    float* sq    = ws + WS_SQ;

    hipLaunchKernelGGL(k_zero,     dim3(5),           dim3(256), 0, stream, ws);
    hipLaunchKernelGGL(k_seg_sums, dim3(1024),        dim3(256), 0, stream, feat, labels, sums, cnts);
    hipLaunchKernelGGL(k_var,      dim3(1024),        dim3(256), 0, stream, feat, labels, sums, cnts, hinge);
    hipLaunchKernelGGL(k_sel,      dim3(32),          dim3(64),  0, stream, le, sel);
    hipLaunchKernelGGL(k_gather,   dim3(32),          dim3(256), 0, stream, feat, sel, ebh, sq);
    hipLaunchKernelGGL(k_edge,     dim3(16, 28, 4),   dim3(256), 0, stream, ebh, sq, edge);
    hipLaunchKernelGGL(k_final,    dim3(1),           dim3(256), 0, stream, sums, cnts, hinge, edge, out);
}